// Round 4
// 18281.812 us; speedup vs baseline: 1.4373x; 1.4373x over previous
//
#include <hip/hip_runtime.h>
#include <hip/hip_fp16.h>
#include <stdint.h>

#define B_  512
#define S_  512
#define IN_ 118
#define H1_ 256
#define H2_ 128

#define NT_  16                 // batch tiles, 32 rows each
#define NS1_ 8                  // layer-1 unit-slice blocks per tile (32 units each)
#define NS2_ 4                  // layer-2 unit-slice blocks per tile (32 units each)
#define NL1_ (NT_*NS1_)         // 128
#define NBLK (NT_*(NS1_+NS2_))  // 192  (< 256 CUs -> co-resident under plain launch)

// Weights are scaled by 2^10 before the fp16 hi/lo split so the lo residuals
// are NORMAL fp16 (unscaled residuals <= 1.5e-5 are all subnormal, quantum
// 2^-24 -> up to ~3e-6 relative systematic weight error). z is unscaled by
// the exact power of two before the bias add.
#define WSCALE    1024.0f
#define WSCALE_I  0.0009765625f

typedef __attribute__((ext_vector_type(8))) short frag8;    // 8 fp16 = 4 VGPRs
typedef __attribute__((ext_vector_type(4))) float facc4;    // MFMA accumulator
typedef unsigned short u16;
typedef unsigned int   u32;

// ---------------- ws layout (bytes) ----------------
#define OFF_W1H 0
#define OFF_W1L 786432
#define OFF_W2H 1572864
#define OFF_W2L 1966080
#define OFF_AR1 2359296
#define OFF_AR2 (OFF_AR1 + 524288)
#define OFF_DN2 (OFF_AR2 + 524288)
#define OFF_HX  (OFF_DN2 + 524288)      // 3932160

#define FIDX(t, bt) ((((t)*16 + (bt)) << 4))

__device__ __forceinline__ void splitf(float v, u16& hi, u16& lo) {
    __half h = __float2half(v);          // RNE
    float hf = __half2float(h);
    __half l = __float2half(v - hf);
    hi = *(u16*)&h; lo = *(u16*)&l;
}

// exact-argument exp: 2^(x*log2e) with double-float argument correction.
__device__ __forceinline__ float exp_(float x) {
    const float A  = 1.44269504f;        // fp32(log2 e)
    const float Ae = 1.9259630e-8f;      // log2(e) - (double)A
    float a = x * A;
    float e = __builtin_fmaf(x, A, -a);
    e = __builtin_fmaf(x, Ae, e);
    float p;
    asm("v_exp_f32 %0, %1" : "=v"(p) : "v"(a));
    return __builtin_fmaf(p * 0.69314718f, e, p);
}
__device__ __forceinline__ float sigm_(float x) {
    return 1.f / (1.f + exp_(fmaxf(-x, -88.f)));
}
__device__ __forceinline__ float tanh_(float x) {
    float ax = fabsf(x);
    float e  = exp_(-2.f * ax);
    float r  = (1.f - e) / (1.f + e);
    return copysignf(r, x);
}
// rsqrt with one Newton refinement (~0.5 ulp)
__device__ __forceinline__ float rsqrt_(float x) {
    float r = rsqrtf(x);
    return r * __builtin_fmaf(-0.5f * x, r * r, 1.5f);
}

// agent-scope full fence: wb(L2) + inv(L1,L2) — cross-XCD visibility point
__device__ __forceinline__ void agent_fence() {
    __builtin_amdgcn_fence(__ATOMIC_SEQ_CST, "agent");
}
__device__ __forceinline__ u32 flag_poll(u32* p) {
    return __hip_atomic_fetch_add(p, 0u, __ATOMIC_RELAXED, __HIP_MEMORY_SCOPE_AGENT);
}
__device__ __forceinline__ void flag_inc(u32* p) {
    __hip_atomic_fetch_add(p, 1u, __ATOMIC_RELAXED, __HIP_MEMORY_SCOPE_AGENT);
}

__global__ void prep_weights(const float* __restrict__ Wf1, const float* __restrict__ Wi1,
                             const float* __restrict__ Wg1, const float* __restrict__ Wo1,
                             const float* __restrict__ Wf2, const float* __restrict__ Wi2,
                             const float* __restrict__ Wg2, const float* __restrict__ Wo2,
                             u16* __restrict__ w1h, u16* __restrict__ w1l,
                             u16* __restrict__ w2h, u16* __restrict__ w2l) {
    int idx = blockIdx.x * 256 + threadIdx.x;
    if (idx >= 589824) return;
    if (idx < 393216) {
        int j  = idx & 7;
        int L  = (idx >> 3) & 63;
        int fr = idx >> 9;                 // tile*12 + kf
        int kf = fr % 12, tile = fr / 12;  // tile = bs*8 + ln
        int bs = tile >> 3, ln = tile & 7;
        int khat = kf*32 + (L >> 4)*8 + j;
        int lc   = ln*16 + (L & 15);
        int g = lc >> 5, unit = bs*32 + (lc & 31);
        const float* Wg[4] = {Wf1, Wi1, Wg1, Wo1};
        float v = 0.f;
        if (khat < IN_)       v = Wg[g][unit*374 + khat];        // x part
        else if (khat >= 128) v = Wg[g][unit*374 + khat - 10];   // h part (pad 118..127 = 0)
        v *= WSCALE;
        u16 hi, lo; splitf(v, hi, lo);
        w1h[idx] = hi; w1l[idx] = lo;
    } else {
        int i2 = idx - 393216;
        int j  = i2 & 7;
        int L  = (i2 >> 3) & 63;
        int fr = i2 >> 9;
        int kf = fr % 12, tile = fr / 12;  // tile = vs*8 + ln
        int vs = tile >> 3, ln = tile & 7;
        int khat = kf*32 + (L >> 4)*8 + j;
        int lc   = ln*16 + (L & 15);
        int g = lc >> 5, unit = vs*32 + (lc & 31);
        const float* Wg[4] = {Wf2, Wi2, Wg2, Wo2};
        float v = Wg[g][unit*384 + khat] * WSCALE;
        u16 hi, lo; splitf(v, hi, lo);
        w2h[i2] = hi; w2l[i2] = lo;
    }
}

// Dynamic LDS (53760 B):
//  0      combH : u16 [32][392]
//  25088  combL : u16 [32][392]
//  50176  float area: bz[128] | gamma/beta tables
// z overlay (scaled by WSCALE): fp32 over comb cols [0,128):
//   lc<64 -> ((float*)combH)[row*196+lc], else ((float*)combL)[row*196+lc-64].

// consumer-side LN + hi/lo split. Two-pass variance (matches reference
// formula mean((h-mu)^2)); grouped-pairwise reduction keeps register
// pressure low (weights occupy 192 VGPRs).
template<int NC>   // cols per thread: 32 (H=256) or 16 (H=128); 8 threads per row
__device__ __forceinline__ void build_ln(u16* combH, u16* combL, int lds_c0,
    const float* __restrict__ src, int Hstr, float invH,
    const float* sG, const float* sB, int tid, int zero)
{
    int row = tid >> 3, tc = tid & 7;
    if (!zero) {
        const float* p = src + (size_t)row*Hstr + tc*NC;
        float v[NC];
        #pragma unroll
        for (int j = 0; j < NC; ++j) v[j] = p[j];
        float p4[NC/4];
        #pragma unroll
        for (int j = 0; j < NC/4; ++j)
            p4[j] = (v[4*j] + v[4*j+1]) + (v[4*j+2] + v[4*j+3]);
        #pragma unroll
        for (int st = 1; st < NC/4; st <<= 1)
            #pragma unroll
            for (int j = 0; j < NC/4; j += 2*st) p4[j] += p4[j+st];
        float s = p4[0];
        #pragma unroll
        for (int off = 1; off < 8; off <<= 1) s += __shfl_xor(s, off, 64);
        float mu = s * invH;
        // second pass: mean((v-mu)^2)
        #pragma unroll
        for (int j = 0; j < NC/4; ++j) {
            float d0 = v[4*j]   - mu, d1 = v[4*j+1] - mu;
            float d2 = v[4*j+2] - mu, d3 = v[4*j+3] - mu;
            p4[j] = (d0*d0 + d1*d1) + (d2*d2 + d3*d3);
        }
        #pragma unroll
        for (int st = 1; st < NC/4; st <<= 1)
            #pragma unroll
            for (int j = 0; j < NC/4; j += 2*st) p4[j] += p4[j+st];
        float sq = p4[0];
        #pragma unroll
        for (int off = 1; off < 8; off <<= 1) sq += __shfl_xor(sq, off, 64);
        float rs = rsqrt_(__builtin_fmaf(sq, invH, 1e-5f));
        #pragma unroll
        for (int g8 = 0; g8 < NC/8; ++g8) {
            frag8 fh, fl;
            #pragma unroll
            for (int j = 0; j < 8; ++j) {
                int u = tc*NC + g8*8 + j;
                float t_ = (v[g8*8+j] - mu)*rs;
                float hn = __builtin_fmaf(t_, sG[u], sB[u]);
                u16 hi, lo; splitf(hn, hi, lo);
                fh[j] = (short)hi; fl[j] = (short)lo;
            }
            *(frag8*)&combH[row*392 + lds_c0 + tc*NC + g8*8] = fh;
            *(frag8*)&combL[row*392 + lds_c0 + tc*NC + g8*8] = fl;
        }
    } else {
        frag8 z = {0,0,0,0,0,0,0,0};
        #pragma unroll
        for (int g8 = 0; g8 < NC/8; ++g8) {
            *(frag8*)&combH[row*392 + lds_c0 + tc*NC + g8*8] = z;
            *(frag8*)&combL[row*392 + lds_c0 + tc*NC + g8*8] = z;
        }
    }
}

__device__ __forceinline__ void gemm_step(const u16* combH, const u16* combL,
    const frag8 (&wH)[2][12], const frag8 (&wL)[2][12], int lane, facc4 (&acc)[2][2])
{
    const int q = lane >> 4, cc = lane & 15;
    #pragma unroll
    for (int kf = 0; kf < 12; ++kf) {
        #pragma unroll
        for (int m = 0; m < 2; ++m) {
            frag8 aH = *(const frag8*)&combH[(m*16+cc)*392 + kf*32 + q*8];
            frag8 aL = *(const frag8*)&combL[(m*16+cc)*392 + kf*32 + q*8];
            #pragma unroll
            for (int e = 0; e < 2; ++e) {
                acc[m][e] = __builtin_amdgcn_mfma_f32_16x16x32_f16(aH, wH[e][kf], acc[m][e], 0, 0, 0);
                acc[m][e] = __builtin_amdgcn_mfma_f32_16x16x32_f16(aL, wH[e][kf], acc[m][e], 0, 0, 0);
                acc[m][e] = __builtin_amdgcn_mfma_f32_16x16x32_f16(aL, wL[e][kf], acc[m][e], 0, 0, 0);
                acc[m][e] = __builtin_amdgcn_mfma_f32_16x16x32_f16(aH, wL[e][kf], acc[m][e], 0, 0, 0);
            }
        }
    }
}

__device__ __forceinline__ void zdump(u16* combH, u16* combL, int w, int lane,
                                      const facc4 (&acc)[2][2])
{
    const int q = lane >> 4, cc = lane & 15;
    float* zH = (float*)combH;
    float* zL = (float*)combL;
    #pragma unroll
    for (int e = 0; e < 2; ++e) {
        int lc = (w*2 + e)*16 + cc;             // plane select is wave-uniform
        float* zp = ((w*2 + e) < 4) ? zH : zL;
        int lcl = lc & 63;
        #pragma unroll
        for (int m = 0; m < 2; ++m)
            #pragma unroll
            for (int r = 0; r < 4; ++r)
                zp[(m*16 + q*4 + r)*196 + lcl] = acc[m][e][r];
    }
}

__device__ __forceinline__ void gates_update(const u16* combH, const u16* combL,
    const float* bz, float* cst, int tid, float* houtBase, int Hstr)
{
    const float* zH = (const float*)combH;
    const float* zL = (const float*)combL;
    const int u = tid & 31, rb = tid >> 5;
    const float bzf = bz[u], bzi = bz[32+u], bzg = bz[64+u], bzo = bz[96+u];
    #pragma unroll
    for (int rr = 0; rr < 4; ++rr) {
        int row = rr*8 + rb;
        float zf = __builtin_fmaf(zH[row*196 + u],      WSCALE_I, bzf);
        float zi = __builtin_fmaf(zH[row*196 + 32 + u], WSCALE_I, bzi);
        float zg = __builtin_fmaf(zL[row*196 + u],      WSCALE_I, bzg);
        float zo = __builtin_fmaf(zL[row*196 + 32 + u], WSCALE_I, bzo);
        float ig = sigm_(zi) * tanh_(zg);
        float c  = __builtin_fmaf(sigm_(zf), cst[rr], ig);
        cst[rr]  = c;
        houtBase[(size_t)row*Hstr + u] = sigm_(zo)*tanh_(c);
    }
}

__global__ __launch_bounds__(256, 1) void lstm_seq(
    const float* __restrict__ x,
    const float* __restrict__ bf1, const float* __restrict__ bi1,
    const float* __restrict__ bg1, const float* __restrict__ bo1,
    const float* __restrict__ bf2, const float* __restrict__ bi2,
    const float* __restrict__ bg2, const float* __restrict__ bo2,
    const float* __restrict__ gamma1, const float* __restrict__ beta1,
    const float* __restrict__ gamma2, const float* __restrict__ beta2,
    const u16* __restrict__ w1h, const u16* __restrict__ w1l,
    const u16* __restrict__ w2h, const u16* __restrict__ w2l,
    float* __restrict__ h1x, float* __restrict__ h2x,
    u32* __restrict__ arrive1, u32* __restrict__ arrive2, u32* __restrict__ done2,
    int R, float* __restrict__ out)
{
    extern __shared__ char smem[];
    u16*   combH = (u16*)smem;
    u16*   combL = (u16*)(smem + 25088);
    float* fA    = (float*)(smem + 50176);
    const int tid  = threadIdx.x;
    const int w    = tid >> 6;
    const int lane = tid & 63;
    const int bid  = blockIdx.x;

    if (bid < NL1_) {
        // ============ LAYER 1 : units [bs*32,+32), rows [bt*32,+32) ============
        const int bt = bid >> 3, bs = bid & 7, b0 = bt * 32;
        float* bz = fA;           // [128]
        float* sG = fA + 128;     // gamma1 [256]
        float* sB = fA + 384;     // beta1  [256]
        if (tid < 128) {
            int g = tid >> 5, unit = bs*32 + (tid & 31);
            const float* bp = (g==0)?bf1:(g==1)?bi1:(g==2)?bg1:bo1;
            bz[tid] = bp[unit];
        }
        sG[tid] = gamma1[tid]; sB[tid] = beta1[tid];
        frag8 wH[2][12], wL[2][12];        // this wave's two n-tiles, resident (192 VGPR)
        #pragma unroll
        for (int e = 0; e < 2; ++e)
            #pragma unroll
            for (int kf = 0; kf < 12; ++kf) {
                size_t base = ((((size_t)bs*8 + (w*2+e))*12 + kf)*64 + lane)*8;
                wH[e][kf] = *(const frag8*)&w1h[base];
                wL[e][kf] = *(const frag8*)&w1l[base];
            }
        float cst[4] = {0.f, 0.f, 0.f, 0.f};   // c-state, registers for whole sequence
        __syncthreads();

        int slotW = 0, slotR = 0;
        for (int t = 0; t < S_; ++t) {
            // ---- x-part build (cols 0..128) — independent of flags, overlaps spin
            {
                int row = tid >> 3, tc = tid & 7;
                const float* xp = &x[((size_t)(b0+row)*S_ + t)*IN_ + tc*16];
                #pragma unroll
                for (int g8 = 0; g8 < 2; ++g8) {
                    frag8 fh, fl;
                    #pragma unroll
                    for (int j = 0; j < 8; ++j) {
                        int col = tc*16 + g8*8 + j;
                        float v = (col < IN_) ? xp[g8*8+j] : 0.f;
                        u16 hi, lo; splitf(v, hi, lo);
                        fh[j] = (short)hi; fl[j] = (short)lo;
                    }
                    *(frag8*)&combH[row*392 + tc*16 + g8*8] = fh;
                    *(frag8*)&combL[row*392 + tc*16 + g8*8] = fl;
                }
            }
            // ---- wait: h1[t-1] produced; slot (t-R) consumed by layer-2
            if (tid == 0) {
                if (t > 0)  while (flag_poll(&arrive1[FIDX(t-1, bt)]) < NS1_) {}
                if (t >= R) while (flag_poll(&done2[FIDX(t-R, bt)])   < NS2_) {}
            }
            __syncthreads();
            agent_fence();
            // ---- h-part build (cols 128..384), consumer-side LN
            build_ln<32>(combH, combL, 128, &h1x[((size_t)slotR*B_ + b0)*H1_], H1_,
                         1.f/H1_, sG, sB, tid, t == 0);
            __syncthreads();
            // ---- GEMM (weights in registers)
            facc4 acc[2][2];
            #pragma unroll
            for (int m = 0; m < 2; ++m)
                #pragma unroll
                for (int e = 0; e < 2; ++e) acc[m][e] = (facc4){0.f,0.f,0.f,0.f};
            gemm_step(combH, combL, wH, wL, lane, acc);
            __syncthreads();
            zdump(combH, combL, w, lane, acc);
            __syncthreads();
            // ---- gates + c/h update; publish raw h (fp32)
            gates_update(combH, combL, bz, cst, tid,
                         &h1x[((size_t)slotW*B_ + b0)*H1_ + bs*32], H1_);
            __syncthreads();
            if (tid == 0) { agent_fence(); flag_inc(&arrive1[FIDX(t, bt)]); }
            slotR = slotW; slotW = (slotW + 1 == R) ? 0 : slotW + 1;
        }
    } else {
        // ============ LAYER 2 : units [vs*32,+32), rows [bt*32,+32) ============
        const int idx = bid - NL1_;
        const int bt = idx >> 2, vs = idx & 3, b0 = bt * 32;
        float* bz  = fA;            // [128]
        float* sG1 = fA + 128;      // gamma1 [256]
        float* sB1 = fA + 384;
        float* sG2 = fA + 640;      // gamma2 [128]
        float* sB2 = fA + 768;
        if (tid < 128) {
            int g = tid >> 5, unit = vs*32 + (tid & 31);
            const float* bp = (g==0)?bf2:(g==1)?bi2:(g==2)?bg2:bo2;
            bz[tid] = bp[unit];
        }
        sG1[tid] = gamma1[tid]; sB1[tid] = beta1[tid];
        if (tid < 128) { sG2[tid] = gamma2[tid]; sB2[tid] = beta2[tid]; }
        frag8 wH[2][12], wL[2][12];
        #pragma unroll
        for (int e = 0; e < 2; ++e)
            #pragma unroll
            for (int kf = 0; kf < 12; ++kf) {
                size_t base = ((((size_t)vs*8 + (w*2+e))*12 + kf)*64 + lane)*8;
                wH[e][kf] = *(const frag8*)&w2h[base];
                wL[e][kf] = *(const frag8*)&w2l[base];
            }
        float cst[4] = {0.f, 0.f, 0.f, 0.f};
        __syncthreads();

        int slotW = 0, slotR = 0, slot1 = 0;
        for (int t = 0; t < S_; ++t) {
            // ---- wait h1[t]; build comb cols [0,256) with LN1
            if (tid == 0) while (flag_poll(&arrive1[FIDX(t, bt)]) < NS1_) {}
            __syncthreads();
            agent_fence();
            build_ln<32>(combH, combL, 0, &h1x[((size_t)slot1*B_ + b0)*H1_], H1_,
                         1.f/H1_, sG1, sB1, tid, 0);
            __syncthreads();
            if (tid == 0) { agent_fence(); flag_inc(&done2[FIDX(t, bt)]); }
            // ---- wait h2[t-1]; build comb cols [256,384) with LN2
            if (t > 0 && tid == 0) while (flag_poll(&arrive2[FIDX(t-1, bt)]) < NS2_) {}
            __syncthreads();
            agent_fence();
            build_ln<16>(combH, combL, 256, &h2x[((size_t)slotR*B_ + b0)*H2_], H2_,
                         1.f/H2_, sG2, sB2, tid, t == 0);
            __syncthreads();
            facc4 acc[2][2];
            #pragma unroll
            for (int m = 0; m < 2; ++m)
                #pragma unroll
                for (int e = 0; e < 2; ++e) acc[m][e] = (facc4){0.f,0.f,0.f,0.f};
            gemm_step(combH, combL, wH, wL, lane, acc);
            __syncthreads();
            zdump(combH, combL, w, lane, acc);
            __syncthreads();
            gates_update(combH, combL, bz, cst, tid,
                         &h2x[((size_t)slotW*B_ + b0)*H2_ + vs*32], H2_);
            __syncthreads();
            if (tid == 0) { agent_fence(); flag_inc(&arrive2[FIDX(t, bt)]); }
            slotR = slotW; slotW = (slotW + 1 == R) ? 0 : slotW + 1;
            slot1 = (slot1 + 1 == R) ? 0 : slot1 + 1;
        }
        // ---- final output: LN(h2[511]) by slice-0 blocks
        if (vs == 0) {
            if (tid == 0) while (flag_poll(&arrive2[FIDX(S_-1, bt)]) < NS2_) {}
            __syncthreads();
            agent_fence();
            int row = tid >> 3, tc = tid & 7;
            const float* p = &h2x[((size_t)slotR*B_ + b0 + row)*H2_ + tc*16];
            float v[16];
            #pragma unroll
            for (int j = 0; j < 16; ++j) v[j] = p[j];
            float p4[4];
            #pragma unroll
            for (int j = 0; j < 4; ++j)
                p4[j] = (v[4*j] + v[4*j+1]) + (v[4*j+2] + v[4*j+3]);
            float s = (p4[0] + p4[1]) + (p4[2] + p4[3]);
            #pragma unroll
            for (int off = 1; off < 8; off <<= 1) s += __shfl_xor(s, off, 64);
            float mu = s * (1.f/H2_);
            #pragma unroll
            for (int j = 0; j < 4; ++j) {
                float d0 = v[4*j]   - mu, d1 = v[4*j+1] - mu;
                float d2 = v[4*j+2] - mu, d3 = v[4*j+3] - mu;
                p4[j] = (d0*d0 + d1*d1) + (d2*d2 + d3*d3);
            }
            float sq = (p4[0] + p4[1]) + (p4[2] + p4[3]);
            #pragma unroll
            for (int off = 1; off < 8; off <<= 1) sq += __shfl_xor(sq, off, 64);
            float rs = rsqrt_(__builtin_fmaf(sq, 1.f/H2_, 1e-5f));
            #pragma unroll
            for (int j = 0; j < 16; ++j) {
                int u = tc*16 + j;
                float t_ = (v[j]-mu)*rs;
                out[((size_t)(b0+row))*H2_ + u] = __builtin_fmaf(t_, sG2[u], sB2[u]);
            }
        }
    }
}

extern "C" void kernel_launch(void* const* d_in, const int* in_sizes, int n_in,
                              void* d_out, int out_size, void* d_ws, size_t ws_size,
                              hipStream_t stream) {
    const float* x      = (const float*)d_in[0];
    const float* Wf1    = (const float*)d_in[1];
    const float* Wi1    = (const float*)d_in[2];
    const float* Wg1    = (const float*)d_in[3];
    const float* Wo1    = (const float*)d_in[4];
    const float* bf1    = (const float*)d_in[5];
    const float* bi1    = (const float*)d_in[6];
    const float* bg1    = (const float*)d_in[7];
    const float* bo1    = (const float*)d_in[8];
    const float* Wf2    = (const float*)d_in[9];
    const float* Wi2    = (const float*)d_in[10];
    const float* Wg2    = (const float*)d_in[11];
    const float* Wo2    = (const float*)d_in[12];
    const float* bf2    = (const float*)d_in[13];
    const float* bi2    = (const float*)d_in[14];
    const float* bg2    = (const float*)d_in[15];
    const float* bo2    = (const float*)d_in[16];
    const float* gamma1 = (const float*)d_in[17];
    const float* beta1  = (const float*)d_in[18];
    const float* gamma2 = (const float*)d_in[19];
    const float* beta2  = (const float*)d_in[20];

    char* ws = (char*)d_ws;
    u16* w1h = (u16*)(ws + OFF_W1H);
    u16* w1l = (u16*)(ws + OFF_W1L);
    u16* w2h = (u16*)(ws + OFF_W2H);
    u16* w2l = (u16*)(ws + OFF_W2L);
    u32* arrive1 = (u32*)(ws + OFF_AR1);
    u32* arrive2 = (u32*)(ws + OFF_AR2);
    u32* done2   = (u32*)(ws + OFF_DN2);

    // exchange-ring depth: per slot 524288 B (h1) + 262144 B (h2)
    int R = (int)((ws_size - OFF_HX) / 786432);
    if (R > 16) R = 16;
    if (R < 2)  R = 2;
    float* h1x = (float*)(ws + OFF_HX);
    float* h2x = (float*)(ws + OFF_HX + (size_t)R * 524288);

    // zero the monotonic per-(step,tile) flag lines
    hipMemsetAsync(ws + OFF_AR1, 0, 3 * 524288, stream);

    prep_weights<<<2304, 256, 0, stream>>>(Wf1, Wi1, Wg1, Wo1, Wf2, Wi2, Wg2, Wo2,
                                           w1h, w1l, w2h, w2l);

    // Plain launch: 192 blocks < 256 CUs, 1 block/CU -> co-resident by construction.
    lstm_seq<<<dim3(NBLK), dim3(256), 53760, stream>>>(
        x, bf1, bi1, bg1, bo1, bf2, bi2, bg2, bo2,
        gamma1, beta1, gamma2, beta2,
        w1h, w1l, w2h, w2l,
        h1x, h2x, arrive1, arrive2, done2,
        R, (float*)d_out);
}

// Round 5
// 7947.664 us; speedup vs baseline: 3.3062x; 2.3003x over previous
//
#include <hip/hip_runtime.h>
#include <hip/hip_fp16.h>
#include <stdint.h>

#define B_  512
#define S_  512
#define IN_ 118
#define H1_ 256
#define H2_ 128

#define NT_  16                 // batch tiles, 32 rows each
#define NS1_ 8                  // layer-1 unit-slice blocks per tile (32 units each)
#define NS2_ 4                  // layer-2 unit-slice blocks per tile (32 units each)
#define NBLK (NT_*(NS1_+NS2_))  // 192  (< 256 CUs -> co-resident under plain launch)

// Weights are scaled by 2^10 before the fp16 hi/lo split so the lo residuals
// are NORMAL fp16. z is unscaled by the exact power of two before bias add.
#define WSCALE    1024.0f
#define WSCALE_I  0.0009765625f

typedef __attribute__((ext_vector_type(8))) short frag8;    // 8 fp16 = 4 VGPRs
typedef __attribute__((ext_vector_type(4))) float facc4;    // MFMA accumulator
typedef unsigned short u16;
typedef unsigned int   u32;

// ---------------- ws layout (bytes) ----------------
// 0        w1h  786432   fp16 [8 bs][8 ln][12 kf][64 lane][8]
// 786432   w1l  786432
// 1572864  w2h  393216
// 1966080  w2l  393216
// 2359296  flag stamps (per-producer words, 64B padded, monotonic t+1):
//          a1  [16 bt][8 bs]x16   8192 B   "h1[t] published"
//          a2  [16 bt][4 vs]x16   4096 B   "h2[t] published"
//          dn2 [16 bt][4 vs]x16   4096 B   "h1[t] consumed by L2"
// 2424832  h1x  float [R][512 b][256 u]   R*524288
//  ...     h2x  float [R][512 b][128 u]   R*262144
// ---------------------------------------------------
#define OFF_W1H 0
#define OFF_W1L 786432
#define OFF_W2H 1572864
#define OFF_W2L 1966080
#define OFF_AR1 2359296
#define OFF_AR2 (OFF_AR1 + 8192)
#define OFF_DN2 (OFF_AR2 + 4096)
#define OFF_HX  (OFF_AR1 + 65536)

#define A1IDX(bt,bs) ((((bt)*8+(bs))<<4))
#define A2IDX(bt,vs) ((((bt)*4+(vs))<<4))

__device__ __forceinline__ void splitf(float v, u16& hi, u16& lo) {
    __half h = __float2half(v);          // RNE
    float hf = __half2float(h);
    __half l = __float2half(v - hf);
    hi = *(u16*)&h; lo = *(u16*)&l;
}

// exact-argument exp: 2^(x*log2e) with double-float argument correction.
__device__ __forceinline__ float exp_(float x) {
    const float A  = 1.44269504f;        // fp32(log2 e)
    const float Ae = 1.9259630e-8f;      // log2(e) - (double)A
    float a = x * A;
    float e = __builtin_fmaf(x, A, -a);
    e = __builtin_fmaf(x, Ae, e);
    float p;
    asm("v_exp_f32 %0, %1" : "=v"(p) : "v"(a));
    return __builtin_fmaf(p * 0.69314718f, e, p);
}
__device__ __forceinline__ float sigm_(float x) {
    return 1.f / (1.f + exp_(fmaxf(-x, -88.f)));
}
__device__ __forceinline__ float tanh_(float x) {
    float ax = fabsf(x);
    float e  = exp_(-2.f * ax);
    float r  = (1.f - e) / (1.f + e);
    return copysignf(r, x);
}
// rsqrt with one Newton refinement (~0.5 ulp)
__device__ __forceinline__ float rsqrt_(float x) {
    float r = rsqrtf(x);
    return r * __builtin_fmaf(-0.5f * x, r * r, 1.5f);
}

// release (producer) / acquire (consumer) agent fences — data side.
__device__ __forceinline__ void rel_fence() {
    __builtin_amdgcn_fence(__ATOMIC_RELEASE, "agent");
}
__device__ __forceinline__ void acq_fence() {
    __builtin_amdgcn_fence(__ATOMIC_ACQUIRE, "agent");
}
// flags: plain agent-scope atomic LOAD/STORE (no RMW -> no ownership
// ping-pong; producers store in parallel to distinct 64B lines).
__device__ __forceinline__ u32 ld_flag(const u32* p) {
    return __hip_atomic_load(p, __ATOMIC_RELAXED, __HIP_MEMORY_SCOPE_AGENT);
}
__device__ __forceinline__ void st_flag(u32* p, u32 v) {
    __hip_atomic_store(p, v, __ATOMIC_RELAXED, __HIP_MEMORY_SCOPE_AGENT);
}

__global__ void prep_weights(const float* __restrict__ Wf1, const float* __restrict__ Wi1,
                             const float* __restrict__ Wg1, const float* __restrict__ Wo1,
                             const float* __restrict__ Wf2, const float* __restrict__ Wi2,
                             const float* __restrict__ Wg2, const float* __restrict__ Wo2,
                             u16* __restrict__ w1h, u16* __restrict__ w1l,
                             u16* __restrict__ w2h, u16* __restrict__ w2l) {
    int idx = blockIdx.x * 256 + threadIdx.x;
    if (idx >= 589824) return;
    if (idx < 393216) {
        int j  = idx & 7;
        int L  = (idx >> 3) & 63;
        int fr = idx >> 9;                 // tile*12 + kf
        int kf = fr % 12, tile = fr / 12;  // tile = bs*8 + ln
        int bs = tile >> 3, ln = tile & 7;
        int khat = kf*32 + (L >> 4)*8 + j;
        int lc   = ln*16 + (L & 15);
        int g = lc >> 5, unit = bs*32 + (lc & 31);
        const float* Wg[4] = {Wf1, Wi1, Wg1, Wo1};
        float v = 0.f;
        if (khat < IN_)       v = Wg[g][unit*374 + khat];        // x part
        else if (khat >= 128) v = Wg[g][unit*374 + khat - 10];   // h part (pad 118..127 = 0)
        v *= WSCALE;
        u16 hi, lo; splitf(v, hi, lo);
        w1h[idx] = hi; w1l[idx] = lo;
    } else {
        int i2 = idx - 393216;
        int j  = i2 & 7;
        int L  = (i2 >> 3) & 63;
        int fr = i2 >> 9;
        int kf = fr % 12, tile = fr / 12;  // tile = vs*8 + ln
        int vs = tile >> 3, ln = tile & 7;
        int khat = kf*32 + (L >> 4)*8 + j;
        int lc   = ln*16 + (L & 15);
        int g = lc >> 5, unit = vs*32 + (lc & 31);
        const float* Wg[4] = {Wf2, Wi2, Wg2, Wo2};
        float v = Wg[g][unit*384 + khat] * WSCALE;
        u16 hi, lo; splitf(v, hi, lo);
        w2h[i2] = hi; w2l[i2] = lo;
    }
}

// Dynamic LDS (53760 B):
//  0      combH : u16 [32][392]
//  25088  combL : u16 [32][392]
//  50176  float area: bz[128] | gamma/beta tables
// z overlay (scaled by WSCALE): fp32 over comb cols [0,128):
//   lc<64 -> ((float*)combH)[row*196+lc], else ((float*)combL)[row*196+lc-64].

template<int NC>   // cols per thread: 32 (H=256) or 16 (H=128); 8 threads per row
__device__ __forceinline__ void build_ln(u16* combH, u16* combL, int lds_c0,
    const float* __restrict__ src, int Hstr, float invH,
    const float* sG, const float* sB, int tid, int zero)
{
    int row = tid >> 3, tc = tid & 7;
    if (!zero) {
        const float* p = src + (size_t)row*Hstr + tc*NC;
        float v[NC];
        #pragma unroll
        for (int j = 0; j < NC; ++j) v[j] = p[j];
        float p4[NC/4];
        #pragma unroll
        for (int j = 0; j < NC/4; ++j)
            p4[j] = (v[4*j] + v[4*j+1]) + (v[4*j+2] + v[4*j+3]);
        #pragma unroll
        for (int st = 1; st < NC/4; st <<= 1)
            #pragma unroll
            for (int j = 0; j < NC/4; j += 2*st) p4[j] += p4[j+st];
        float s = p4[0];
        #pragma unroll
        for (int off = 1; off < 8; off <<= 1) s += __shfl_xor(s, off, 64);
        float mu = s * invH;
        #pragma unroll
        for (int j = 0; j < NC/4; ++j) {
            float d0 = v[4*j]   - mu, d1 = v[4*j+1] - mu;
            float d2 = v[4*j+2] - mu, d3 = v[4*j+3] - mu;
            p4[j] = (d0*d0 + d1*d1) + (d2*d2 + d3*d3);
        }
        #pragma unroll
        for (int st = 1; st < NC/4; st <<= 1)
            #pragma unroll
            for (int j = 0; j < NC/4; j += 2*st) p4[j] += p4[j+st];
        float sq = p4[0];
        #pragma unroll
        for (int off = 1; off < 8; off <<= 1) sq += __shfl_xor(sq, off, 64);
        float rs = rsqrt_(__builtin_fmaf(sq, invH, 1e-5f));
        #pragma unroll
        for (int g8 = 0; g8 < NC/8; ++g8) {
            frag8 fh, fl;
            #pragma unroll
            for (int j = 0; j < 8; ++j) {
                int u = tc*NC + g8*8 + j;
                float t_ = (v[g8*8+j] - mu)*rs;
                float hn = __builtin_fmaf(t_, sG[u], sB[u]);
                u16 hi, lo; splitf(hn, hi, lo);
                fh[j] = (short)hi; fl[j] = (short)lo;
            }
            *(frag8*)&combH[row*392 + lds_c0 + tc*NC + g8*8] = fh;
            *(frag8*)&combL[row*392 + lds_c0 + tc*NC + g8*8] = fl;
        }
    } else {
        frag8 z = {0,0,0,0,0,0,0,0};
        #pragma unroll
        for (int g8 = 0; g8 < NC/8; ++g8) {
            *(frag8*)&combH[row*392 + lds_c0 + tc*NC + g8*8] = z;
            *(frag8*)&combL[row*392 + lds_c0 + tc*NC + g8*8] = z;
        }
    }
}

__device__ __forceinline__ void gemm_step(const u16* combH, const u16* combL,
    const frag8 (&wH)[2][12], const frag8 (&wL)[2][12], int lane, facc4 (&acc)[2][2])
{
    const int q = lane >> 4, cc = lane & 15;
    #pragma unroll
    for (int kf = 0; kf < 12; ++kf) {
        #pragma unroll
        for (int m = 0; m < 2; ++m) {
            frag8 aH = *(const frag8*)&combH[(m*16+cc)*392 + kf*32 + q*8];
            frag8 aL = *(const frag8*)&combL[(m*16+cc)*392 + kf*32 + q*8];
            #pragma unroll
            for (int e = 0; e < 2; ++e) {
                acc[m][e] = __builtin_amdgcn_mfma_f32_16x16x32_f16(aH, wH[e][kf], acc[m][e], 0, 0, 0);
                acc[m][e] = __builtin_amdgcn_mfma_f32_16x16x32_f16(aL, wH[e][kf], acc[m][e], 0, 0, 0);
                acc[m][e] = __builtin_amdgcn_mfma_f32_16x16x32_f16(aL, wL[e][kf], acc[m][e], 0, 0, 0);
                acc[m][e] = __builtin_amdgcn_mfma_f32_16x16x32_f16(aH, wL[e][kf], acc[m][e], 0, 0, 0);
            }
        }
    }
}

__device__ __forceinline__ void zdump(u16* combH, u16* combL, int w, int lane,
                                      const facc4 (&acc)[2][2])
{
    const int q = lane >> 4, cc = lane & 15;
    float* zH = (float*)combH;
    float* zL = (float*)combL;
    #pragma unroll
    for (int e = 0; e < 2; ++e) {
        int lc = (w*2 + e)*16 + cc;             // plane select is wave-uniform
        float* zp = ((w*2 + e) < 4) ? zH : zL;
        int lcl = lc & 63;
        #pragma unroll
        for (int m = 0; m < 2; ++m)
            #pragma unroll
            for (int r = 0; r < 4; ++r)
                zp[(m*16 + q*4 + r)*196 + lcl] = acc[m][e][r];
    }
}

__device__ __forceinline__ void gates_update(const u16* combH, const u16* combL,
    const float* bz, float* cst, int tid, float* houtBase, int Hstr)
{
    const float* zH = (const float*)combH;
    const float* zL = (const float*)combL;
    const int u = tid & 31, rb = tid >> 5;
    const float bzf = bz[u], bzi = bz[32+u], bzg = bz[64+u], bzo = bz[96+u];
    #pragma unroll
    for (int rr = 0; rr < 4; ++rr) {
        int row = rr*8 + rb;
        float zf = __builtin_fmaf(zH[row*196 + u],      WSCALE_I, bzf);
        float zi = __builtin_fmaf(zH[row*196 + 32 + u], WSCALE_I, bzi);
        float zg = __builtin_fmaf(zL[row*196 + u],      WSCALE_I, bzg);
        float zo = __builtin_fmaf(zL[row*196 + 32 + u], WSCALE_I, bzo);
        float ig = sigm_(zi) * tanh_(zg);
        float c  = __builtin_fmaf(sigm_(zf), cst[rr], ig);
        cst[rr]  = c;
        houtBase[(size_t)row*Hstr + u] = sigm_(zo)*tanh_(c);
    }
}

__global__ __launch_bounds__(256, 1) void lstm_seq(
    const float* __restrict__ x,
    const float* __restrict__ bf1, const float* __restrict__ bi1,
    const float* __restrict__ bg1, const float* __restrict__ bo1,
    const float* __restrict__ bf2, const float* __restrict__ bi2,
    const float* __restrict__ bg2, const float* __restrict__ bo2,
    const float* __restrict__ gamma1, const float* __restrict__ beta1,
    const float* __restrict__ gamma2, const float* __restrict__ beta2,
    const u16* __restrict__ w1h, const u16* __restrict__ w1l,
    const u16* __restrict__ w2h, const u16* __restrict__ w2l,
    float* __restrict__ h1x, float* __restrict__ h2x,
    u32* __restrict__ a1, u32* __restrict__ a2, u32* __restrict__ dn2,
    int R, float* __restrict__ out)
{
    extern __shared__ char smem[];
    u16*   combH = (u16*)smem;
    u16*   combL = (u16*)(smem + 25088);
    float* fA    = (float*)(smem + 50176);
    const int tid  = threadIdx.x;
    const int w    = tid >> 6;
    const int lane = tid & 63;

    // XCD-local tile mapping: hw blocks round-robin XCDs (bid%8). Put all 12
    // blocks of a tile on one XCD: xcd k hosts tiles k and k+8 (24 blocks/XCD).
    const int bhw  = blockIdx.x;
    const int xcd  = bhw & 7, slot = bhw >> 3;      // slot 0..23
    const int grp  = (slot >= 12) ? 1 : 0;
    const int sl   = slot - grp*12;                 // 0..11
    const int bt   = xcd + 8*grp;                   // tile 0..15
    const int b0   = bt * 32;

    if (sl < 8) {
        // ============ LAYER 1 : units [bs*32,+32), rows [b0,+32) ============
        const int bs = sl;
        float* bz = fA;           // [128]
        float* sG = fA + 128;     // gamma1 [256]
        float* sB = fA + 384;     // beta1  [256]
        if (tid < 128) {
            int g = tid >> 5, unit = bs*32 + (tid & 31);
            const float* bp = (g==0)?bf1:(g==1)?bi1:(g==2)?bg1:bo1;
            bz[tid] = bp[unit];
        }
        sG[tid] = gamma1[tid]; sB[tid] = beta1[tid];
        frag8 wH[2][12], wL[2][12];        // this wave's two n-tiles, resident
        #pragma unroll
        for (int e = 0; e < 2; ++e)
            #pragma unroll
            for (int kf = 0; kf < 12; ++kf) {
                size_t base = ((((size_t)bs*8 + (w*2+e))*12 + kf)*64 + lane)*8;
                wH[e][kf] = *(const frag8*)&w1h[base];
                wL[e][kf] = *(const frag8*)&w1l[base];
            }
        float cst[4] = {0.f, 0.f, 0.f, 0.f};   // c-state, registers for whole sequence
        __syncthreads();

        int slotW = 0, slotR = 0;
        for (int t = 0; t < S_; ++t) {
            // ---- x-part build (cols 0..128) — overlaps sibling publication
            {
                int row = tid >> 3, tc = tid & 7;
                const float* xp = &x[((size_t)(b0+row)*S_ + t)*IN_ + tc*16];
                #pragma unroll
                for (int g8 = 0; g8 < 2; ++g8) {
                    frag8 fh, fl;
                    #pragma unroll
                    for (int j = 0; j < 8; ++j) {
                        int col = tc*16 + g8*8 + j;
                        float v = (col < IN_) ? xp[g8*8+j] : 0.f;
                        u16 hi, lo; splitf(v, hi, lo);
                        fh[j] = (short)hi; fl[j] = (short)lo;
                    }
                    *(frag8*)&combH[row*392 + tc*16 + g8*8] = fh;
                    *(frag8*)&combL[row*392 + tc*16 + g8*8] = fl;
                }
            }
            // ---- parallel-lane poll: h1[t-1] published (8), slot freed by L2 (4)
            {
                u32 need = 0; u32* p = nullptr;
                if (tid < 8)                    { p = &a1[A1IDX(bt, tid)];    need = (u32)t; }
                else if (tid < 12 && t >= R)    { p = &dn2[A2IDX(bt, tid-8)]; need = (u32)(t - R + 1); }
                if (need) while (ld_flag(p) < need) {}
            }
            __syncthreads();
            acq_fence();
            // ---- h-part build (cols 128..384), consumer-side LN
            build_ln<32>(combH, combL, 128, &h1x[((size_t)slotR*B_ + b0)*H1_], H1_,
                         1.f/H1_, sG, sB, tid, t == 0);
            __syncthreads();
            // ---- GEMM (weights in registers)
            facc4 acc[2][2];
            #pragma unroll
            for (int m = 0; m < 2; ++m)
                #pragma unroll
                for (int e = 0; e < 2; ++e) acc[m][e] = (facc4){0.f,0.f,0.f,0.f};
            gemm_step(combH, combL, wH, wL, lane, acc);
            __syncthreads();
            zdump(combH, combL, w, lane, acc);
            __syncthreads();
            // ---- gates + c/h update; publish raw h (fp32)
            gates_update(combH, combL, bz, cst, tid,
                         &h1x[((size_t)slotW*B_ + b0)*H1_ + bs*32], H1_);
            __syncthreads();
            if (tid == 0) { rel_fence(); st_flag(&a1[A1IDX(bt, bs)], (u32)(t + 1)); }
            slotR = slotW; slotW = (slotW + 1 == R) ? 0 : slotW + 1;
        }
    } else {
        // ============ LAYER 2 : units [vs*32,+32), rows [b0,+32) ============
        const int vs = sl - 8;
        float* bz  = fA;            // [128]
        float* sG1 = fA + 128;      // gamma1 [256]
        float* sB1 = fA + 384;
        float* sG2 = fA + 640;      // gamma2 [128]
        float* sB2 = fA + 768;
        if (tid < 128) {
            int g = tid >> 5, unit = vs*32 + (tid & 31);
            const float* bp = (g==0)?bf2:(g==1)?bi2:(g==2)?bg2:bo2;
            bz[tid] = bp[unit];
        }
        sG1[tid] = gamma1[tid]; sB1[tid] = beta1[tid];
        if (tid < 128) { sG2[tid] = gamma2[tid]; sB2[tid] = beta2[tid]; }
        frag8 wH[2][12], wL[2][12];
        #pragma unroll
        for (int e = 0; e < 2; ++e)
            #pragma unroll
            for (int kf = 0; kf < 12; ++kf) {
                size_t base = ((((size_t)vs*8 + (w*2+e))*12 + kf)*64 + lane)*8;
                wH[e][kf] = *(const frag8*)&w2h[base];
                wL[e][kf] = *(const frag8*)&w2l[base];
            }
        float cst[4] = {0.f, 0.f, 0.f, 0.f};
        __syncthreads();

        int slotW = 0, slotR = 0, slot1 = 0;
        for (int t = 0; t < S_; ++t) {
            // ---- merged poll: h1[t] (8 lanes) + h2[t-1] (4 lanes)
            {
                u32 need = 0; u32* p = nullptr;
                if (tid < 8)                  { p = &a1[A1IDX(bt, tid)];   need = (u32)(t + 1); }
                else if (tid < 12 && t > 0)   { p = &a2[A2IDX(bt, tid-8)]; need = (u32)t; }
                if (need) while (ld_flag(p) < need) {}
            }
            __syncthreads();
            acq_fence();
            build_ln<32>(combH, combL, 0, &h1x[((size_t)slot1*B_ + b0)*H1_], H1_,
                         1.f/H1_, sG1, sB1, tid, 0);
            build_ln<16>(combH, combL, 256, &h2x[((size_t)slotR*B_ + b0)*H2_], H2_,
                         1.f/H2_, sG2, sB2, tid, t == 0);
            __syncthreads();
            // consumption token: h1x slot may be recycled (reads drained by barrier)
            if (tid == 0) st_flag(&dn2[A2IDX(bt, vs)], (u32)(t + 1));
            facc4 acc[2][2];
            #pragma unroll
            for (int m = 0; m < 2; ++m)
                #pragma unroll
                for (int e = 0; e < 2; ++e) acc[m][e] = (facc4){0.f,0.f,0.f,0.f};
            gemm_step(combH, combL, wH, wL, lane, acc);
            __syncthreads();
            zdump(combH, combL, w, lane, acc);
            __syncthreads();
            gates_update(combH, combL, bz, cst, tid,
                         &h2x[((size_t)slotW*B_ + b0)*H2_ + vs*32], H2_);
            __syncthreads();
            if (tid == 0) { rel_fence(); st_flag(&a2[A2IDX(bt, vs)], (u32)(t + 1)); }
            slotR = slotW; slotW = (slotW + 1 == R) ? 0 : slotW + 1;
            slot1 = (slot1 + 1 == R) ? 0 : slot1 + 1;
        }
        // ---- final output: LN(h2[511]) by slice-0 blocks
        if (vs == 0) {
            if (tid < 4) { u32* p = &a2[A2IDX(bt, tid)]; while (ld_flag(p) < (u32)S_) {} }
            __syncthreads();
            acq_fence();
            int row = tid >> 3, tc = tid & 7;
            const float* p = &h2x[((size_t)slotR*B_ + b0 + row)*H2_ + tc*16];
            float v[16];
            #pragma unroll
            for (int j = 0; j < 16; ++j) v[j] = p[j];
            float p4[4];
            #pragma unroll
            for (int j = 0; j < 4; ++j)
                p4[j] = (v[4*j] + v[4*j+1]) + (v[4*j+2] + v[4*j+3]);
            float s = (p4[0] + p4[1]) + (p4[2] + p4[3]);
            #pragma unroll
            for (int off = 1; off < 8; off <<= 1) s += __shfl_xor(s, off, 64);
            float mu = s * (1.f/H2_);
            #pragma unroll
            for (int j = 0; j < 4; ++j) {
                float d0 = v[4*j]   - mu, d1 = v[4*j+1] - mu;
                float d2 = v[4*j+2] - mu, d3 = v[4*j+3] - mu;
                p4[j] = (d0*d0 + d1*d1) + (d2*d2 + d3*d3);
            }
            float sq = (p4[0] + p4[1]) + (p4[2] + p4[3]);
            #pragma unroll
            for (int off = 1; off < 8; off <<= 1) sq += __shfl_xor(sq, off, 64);
            float rs = rsqrt_(__builtin_fmaf(sq, 1.f/H2_, 1e-5f));
            #pragma unroll
            for (int j = 0; j < 16; ++j) {
                int u = tc*16 + j;
                float t_ = (v[j]-mu)*rs;
                out[((size_t)(b0+row))*H2_ + u] = __builtin_fmaf(t_, sG2[u], sB2[u]);
            }
        }
    }
}

extern "C" void kernel_launch(void* const* d_in, const int* in_sizes, int n_in,
                              void* d_out, int out_size, void* d_ws, size_t ws_size,
                              hipStream_t stream) {
    const float* x      = (const float*)d_in[0];
    const float* Wf1    = (const float*)d_in[1];
    const float* Wi1    = (const float*)d_in[2];
    const float* Wg1    = (const float*)d_in[3];
    const float* Wo1    = (const float*)d_in[4];
    const float* bf1    = (const float*)d_in[5];
    const float* bi1    = (const float*)d_in[6];
    const float* bg1    = (const float*)d_in[7];
    const float* bo1    = (const float*)d_in[8];
    const float* Wf2    = (const float*)d_in[9];
    const float* Wi2    = (const float*)d_in[10];
    const float* Wg2    = (const float*)d_in[11];
    const float* Wo2    = (const float*)d_in[12];
    const float* bf2    = (const float*)d_in[13];
    const float* bi2    = (const float*)d_in[14];
    const float* bg2    = (const float*)d_in[15];
    const float* bo2    = (const float*)d_in[16];
    const float* gamma1 = (const float*)d_in[17];
    const float* beta1  = (const float*)d_in[18];
    const float* gamma2 = (const float*)d_in[19];
    const float* beta2  = (const float*)d_in[20];

    char* ws = (char*)d_ws;
    u16* w1h = (u16*)(ws + OFF_W1H);
    u16* w1l = (u16*)(ws + OFF_W1L);
    u16* w2h = (u16*)(ws + OFF_W2H);
    u16* w2l = (u16*)(ws + OFF_W2L);
    u32* a1  = (u32*)(ws + OFF_AR1);
    u32* a2  = (u32*)(ws + OFF_AR2);
    u32* dn2 = (u32*)(ws + OFF_DN2);

    // exchange-ring depth: per slot 524288 B (h1) + 262144 B (h2)
    int R = (int)((ws_size - OFF_HX) / 786432);
    if (R > 16) R = 16;
    if (R < 2)  R = 2;
    float* h1x = (float*)(ws + OFF_HX);
    float* h2x = (float*)(ws + OFF_HX + (size_t)R * 524288);

    // zero the stamped flag words
    hipMemsetAsync(ws + OFF_AR1, 0, 65536, stream);

    prep_weights<<<2304, 256, 0, stream>>>(Wf1, Wi1, Wg1, Wo1, Wf2, Wi2, Wg2, Wo2,
                                           w1h, w1l, w2h, w2l);

    // Plain launch: 192 blocks < 256 CUs, 1 block/CU -> co-resident by construction.
    lstm_seq<<<dim3(NBLK), dim3(256), 53760, stream>>>(
        x, bf1, bi1, bg1, bo1, bf2, bi2, bg2, bo2,
        gamma1, beta1, gamma2, beta2,
        w1h, w1l, w2h, w2l,
        h1x, h2x, a1, a2, dn2,
        R, (float*)d_out);
}

// Round 6
// 5151.976 us; speedup vs baseline: 5.1003x; 1.5426x over previous
//
#include <hip/hip_runtime.h>
#include <hip/hip_fp16.h>
#include <stdint.h>

#define B_  512
#define S_  512
#define IN_ 118
#define H1_ 256
#define H2_ 128

#define NT_  16                 // batch tiles, 32 rows each
#define NS1_ 8                  // layer-1 unit-slice blocks per tile (32 units each)
#define NS2_ 4                  // layer-2 unit-slice blocks per tile (32 units each)
#define NBLK (NT_*(NS1_+NS2_))  // 192  (< 256 CUs -> co-resident under plain launch)

// Weights are scaled by 2^10 before the fp16 hi/lo split so the lo residuals
// are NORMAL fp16. z is unscaled by the exact power of two before bias add.
#define WSCALE    1024.0f
#define WSCALE_I  0.0009765625f

typedef __attribute__((ext_vector_type(8))) short frag8;    // 8 fp16 = 4 VGPRs
typedef __attribute__((ext_vector_type(4))) float facc4;    // MFMA accumulator
typedef unsigned short u16;
typedef unsigned int   u32;

// ---------------- ws layout (bytes) ----------------
// 0        w1h  786432   fp16 [8 bs][8 ln][12 kf][64 lane][8]
// 786432   w1l  786432
// 1572864  w2h  393216
// 1966080  w2l  393216
// 2359296  flag stamps (per-producer words, 64B padded, monotonic t+1):
//          a1  [16 bt][8 bs]x16   8192 B   "h1[t] published"
//          a2  [16 bt][4 vs]x16   4096 B   "h2[t] published"
//          dn2 [16 bt][4 vs]x16   4096 B   "h1[t] consumed by L2"
// 2424832  h1x  float [R][512 b][256 u]   R*524288
//  ...     h2x  float [R][512 b][128 u]   R*262144
// ---------------------------------------------------
#define OFF_W1H 0
#define OFF_W1L 786432
#define OFF_W2H 1572864
#define OFF_W2L 1966080
#define OFF_AR1 2359296
#define OFF_AR2 (OFF_AR1 + 8192)
#define OFF_DN2 (OFF_AR2 + 4096)
#define OFF_HX  (OFF_AR1 + 65536)

#define A1IDX(bt,bs) ((((bt)*8+(bs))<<4))
#define A2IDX(bt,vs) ((((bt)*4+(vs))<<4))

__device__ __forceinline__ void splitf(float v, u16& hi, u16& lo) {
    __half h = __float2half(v);          // RNE
    float hf = __half2float(h);
    __half l = __float2half(v - hf);
    hi = *(u16*)&h; lo = *(u16*)&l;
}

// exact-argument exp: 2^(x*log2e) with double-float argument correction.
__device__ __forceinline__ float exp_(float x) {
    const float A  = 1.44269504f;        // fp32(log2 e)
    const float Ae = 1.9259630e-8f;      // log2(e) - (double)A
    float a = x * A;
    float e = __builtin_fmaf(x, A, -a);
    e = __builtin_fmaf(x, Ae, e);
    float p;
    asm("v_exp_f32 %0, %1" : "=v"(p) : "v"(a));
    return __builtin_fmaf(p * 0.69314718f, e, p);
}
__device__ __forceinline__ float sigm_(float x) {
    return 1.f / (1.f + exp_(fmaxf(-x, -88.f)));
}
__device__ __forceinline__ float tanh_(float x) {
    float ax = fabsf(x);
    float e  = exp_(-2.f * ax);
    float r  = (1.f - e) / (1.f + e);
    return copysignf(r, x);
}
// rsqrt with one Newton refinement (~0.5 ulp)
__device__ __forceinline__ float rsqrt_(float x) {
    float r = rsqrtf(x);
    return r * __builtin_fmaf(-0.5f * x, r * r, 1.5f);
}

// Coherence-point accesses (agent-scope relaxed atomics). These bypass stale
// caches to the same visibility point the flags use — proven cross-XCD in
// earlier rounds — so NO cache-walk fences (wbl2/inv) are needed anywhere.
// Ordering: producer's __syncthreads drains vmcnt (stores complete) before
// the flag store; consumer polls, barriers, then issues data loads.
__device__ __forceinline__ u32 ld_flag(const u32* p) {
    return __hip_atomic_load(p, __ATOMIC_RELAXED, __HIP_MEMORY_SCOPE_AGENT);
}
__device__ __forceinline__ void st_flag(u32* p, u32 v) {
    __hip_atomic_store(p, v, __ATOMIC_RELAXED, __HIP_MEMORY_SCOPE_AGENT);
}
__device__ __forceinline__ float ld_coh(const float* p) {
    return __hip_atomic_load(p, __ATOMIC_RELAXED, __HIP_MEMORY_SCOPE_AGENT);
}
__device__ __forceinline__ void st_coh(float* p, float v) {
    __hip_atomic_store(p, v, __ATOMIC_RELAXED, __HIP_MEMORY_SCOPE_AGENT);
}

__global__ void prep_weights(const float* __restrict__ Wf1, const float* __restrict__ Wi1,
                             const float* __restrict__ Wg1, const float* __restrict__ Wo1,
                             const float* __restrict__ Wf2, const float* __restrict__ Wi2,
                             const float* __restrict__ Wg2, const float* __restrict__ Wo2,
                             u16* __restrict__ w1h, u16* __restrict__ w1l,
                             u16* __restrict__ w2h, u16* __restrict__ w2l) {
    int idx = blockIdx.x * 256 + threadIdx.x;
    if (idx >= 589824) return;
    if (idx < 393216) {
        int j  = idx & 7;
        int L  = (idx >> 3) & 63;
        int fr = idx >> 9;                 // tile*12 + kf
        int kf = fr % 12, tile = fr / 12;  // tile = bs*8 + ln
        int bs = tile >> 3, ln = tile & 7;
        int khat = kf*32 + (L >> 4)*8 + j;
        int lc   = ln*16 + (L & 15);
        int g = lc >> 5, unit = bs*32 + (lc & 31);
        const float* Wg[4] = {Wf1, Wi1, Wg1, Wo1};
        float v = 0.f;
        if (khat < IN_)       v = Wg[g][unit*374 + khat];        // x part
        else if (khat >= 128) v = Wg[g][unit*374 + khat - 10];   // h part (pad 118..127 = 0)
        v *= WSCALE;
        u16 hi, lo; splitf(v, hi, lo);
        w1h[idx] = hi; w1l[idx] = lo;
    } else {
        int i2 = idx - 393216;
        int j  = i2 & 7;
        int L  = (i2 >> 3) & 63;
        int fr = i2 >> 9;
        int kf = fr % 12, tile = fr / 12;  // tile = vs*8 + ln
        int vs = tile >> 3, ln = tile & 7;
        int khat = kf*32 + (L >> 4)*8 + j;
        int lc   = ln*16 + (L & 15);
        int g = lc >> 5, unit = vs*32 + (lc & 31);
        const float* Wg[4] = {Wf2, Wi2, Wg2, Wo2};
        float v = Wg[g][unit*384 + khat] * WSCALE;
        u16 hi, lo; splitf(v, hi, lo);
        w2h[i2] = hi; w2l[i2] = lo;
    }
}

// Dynamic LDS (53760 B):
//  0      combH : u16 [32][392]   (row pitch 784 B = 49×16B, odd -> rows rotate slots)
//  25088  combL : u16 [32][392]
//  50176  float area: bz[128] | gamma/beta tables
// z overlay (scaled by WSCALE): fp32 over comb cols [0,128):
//   lc<64 -> ((float*)combH)[row*196+lc], else ((float*)combL)[row*196+lc-64].

// consumer-side LN + hi/lo split. Column assignment u = g8*64 + tc*8 + j:
// per-instruction LDS byte stride across threads = 16B -> 8 distinct 16B slots
// (the old tc*NC mapping was 64B stride -> 4-way bank conflict).
template<int NC>   // cols per thread: 32 (H=256) or 16 (H=128); 8 threads per row
__device__ __forceinline__ void build_ln(u16* combH, u16* combL, int lds_c0,
    const float* __restrict__ src, int Hstr, float invH,
    const float* sG, const float* sB, int tid, int zero)
{
    int row = tid >> 3, tc = tid & 7;
    if (!zero) {
        const float* p = src + (size_t)row*Hstr;
        float v[NC];
        #pragma unroll
        for (int g8 = 0; g8 < NC/8; ++g8)
            #pragma unroll
            for (int j = 0; j < 8; ++j)
                v[g8*8+j] = ld_coh(&p[g8*64 + tc*8 + j]);
        float p4[NC/4];
        #pragma unroll
        for (int j = 0; j < NC/4; ++j)
            p4[j] = (v[4*j] + v[4*j+1]) + (v[4*j+2] + v[4*j+3]);
        #pragma unroll
        for (int st = 1; st < NC/4; st <<= 1)
            #pragma unroll
            for (int j = 0; j < NC/4; j += 2*st) p4[j] += p4[j+st];
        float s = p4[0];
        #pragma unroll
        for (int off = 1; off < 8; off <<= 1) s += __shfl_xor(s, off, 64);
        float mu = s * invH;
        #pragma unroll
        for (int j = 0; j < NC/4; ++j) {
            float d0 = v[4*j]   - mu, d1 = v[4*j+1] - mu;
            float d2 = v[4*j+2] - mu, d3 = v[4*j+3] - mu;
            p4[j] = (d0*d0 + d1*d1) + (d2*d2 + d3*d3);
        }
        #pragma unroll
        for (int st = 1; st < NC/4; st <<= 1)
            #pragma unroll
            for (int j = 0; j < NC/4; j += 2*st) p4[j] += p4[j+st];
        float sq = p4[0];
        #pragma unroll
        for (int off = 1; off < 8; off <<= 1) sq += __shfl_xor(sq, off, 64);
        float rs = rsqrt_(__builtin_fmaf(sq, invH, 1e-5f));
        #pragma unroll
        for (int g8 = 0; g8 < NC/8; ++g8) {
            frag8 fh, fl;
            #pragma unroll
            for (int j = 0; j < 8; ++j) {
                int u = g8*64 + tc*8 + j;
                float t_ = (v[g8*8+j] - mu)*rs;
                float hn = __builtin_fmaf(t_, sG[u], sB[u]);
                u16 hi, lo; splitf(hn, hi, lo);
                fh[j] = (short)hi; fl[j] = (short)lo;
            }
            *(frag8*)&combH[row*392 + lds_c0 + g8*64 + tc*8] = fh;
            *(frag8*)&combL[row*392 + lds_c0 + g8*64 + tc*8] = fl;
        }
    } else {
        frag8 z = {0,0,0,0,0,0,0,0};
        #pragma unroll
        for (int g8 = 0; g8 < NC/8; ++g8) {
            *(frag8*)&combH[row*392 + lds_c0 + g8*64 + tc*8] = z;
            *(frag8*)&combL[row*392 + lds_c0 + g8*64 + tc*8] = z;
        }
    }
}

__device__ __forceinline__ void gemm_step(const u16* combH, const u16* combL,
    const frag8 (&wH)[2][12], const frag8 (&wL)[2][12], int lane, facc4 (&acc)[2][2])
{
    const int q = lane >> 4, cc = lane & 15;
    #pragma unroll
    for (int kf = 0; kf < 12; ++kf) {
        #pragma unroll
        for (int m = 0; m < 2; ++m) {
            frag8 aH = *(const frag8*)&combH[(m*16+cc)*392 + kf*32 + q*8];
            frag8 aL = *(const frag8*)&combL[(m*16+cc)*392 + kf*32 + q*8];
            #pragma unroll
            for (int e = 0; e < 2; ++e) {
                acc[m][e] = __builtin_amdgcn_mfma_f32_16x16x32_f16(aH, wH[e][kf], acc[m][e], 0, 0, 0);
                acc[m][e] = __builtin_amdgcn_mfma_f32_16x16x32_f16(aL, wH[e][kf], acc[m][e], 0, 0, 0);
                acc[m][e] = __builtin_amdgcn_mfma_f32_16x16x32_f16(aL, wL[e][kf], acc[m][e], 0, 0, 0);
                acc[m][e] = __builtin_amdgcn_mfma_f32_16x16x32_f16(aH, wL[e][kf], acc[m][e], 0, 0, 0);
            }
        }
    }
}

__device__ __forceinline__ void zdump(u16* combH, u16* combL, int w, int lane,
                                      const facc4 (&acc)[2][2])
{
    const int q = lane >> 4, cc = lane & 15;
    float* zH = (float*)combH;
    float* zL = (float*)combL;
    #pragma unroll
    for (int e = 0; e < 2; ++e) {
        int lc = (w*2 + e)*16 + cc;             // plane select is wave-uniform
        float* zp = ((w*2 + e) < 4) ? zH : zL;
        int lcl = lc & 63;
        #pragma unroll
        for (int m = 0; m < 2; ++m)
            #pragma unroll
            for (int r = 0; r < 4; ++r)
                zp[(m*16 + q*4 + r)*196 + lcl] = acc[m][e][r];
    }
}

__device__ __forceinline__ void gates_update(const u16* combH, const u16* combL,
    const float* bz, float* cst, int tid, float* houtBase, int Hstr)
{
    const float* zH = (const float*)combH;
    const float* zL = (const float*)combL;
    const int u = tid & 31, rb = tid >> 5;
    const float bzf = bz[u], bzi = bz[32+u], bzg = bz[64+u], bzo = bz[96+u];
    #pragma unroll
    for (int rr = 0; rr < 4; ++rr) {
        int row = rr*8 + rb;
        float zf = __builtin_fmaf(zH[row*196 + u],      WSCALE_I, bzf);
        float zi = __builtin_fmaf(zH[row*196 + 32 + u], WSCALE_I, bzi);
        float zg = __builtin_fmaf(zL[row*196 + u],      WSCALE_I, bzg);
        float zo = __builtin_fmaf(zL[row*196 + 32 + u], WSCALE_I, bzo);
        float ig = sigm_(zi) * tanh_(zg);
        float c  = __builtin_fmaf(sigm_(zf), cst[rr], ig);
        cst[rr]  = c;
        st_coh(&houtBase[(size_t)row*Hstr + u], sigm_(zo)*tanh_(c));
    }
}

__global__ __launch_bounds__(256, 1) void lstm_seq(
    const float* __restrict__ x,
    const float* __restrict__ bf1, const float* __restrict__ bi1,
    const float* __restrict__ bg1, const float* __restrict__ bo1,
    const float* __restrict__ bf2, const float* __restrict__ bi2,
    const float* __restrict__ bg2, const float* __restrict__ bo2,
    const float* __restrict__ gamma1, const float* __restrict__ beta1,
    const float* __restrict__ gamma2, const float* __restrict__ beta2,
    const u16* __restrict__ w1h, const u16* __restrict__ w1l,
    const u16* __restrict__ w2h, const u16* __restrict__ w2l,
    float* __restrict__ h1x, float* __restrict__ h2x,
    u32* __restrict__ a1, u32* __restrict__ a2, u32* __restrict__ dn2,
    int R, float* __restrict__ out)
{
    extern __shared__ char smem[];
    u16*   combH = (u16*)smem;
    u16*   combL = (u16*)(smem + 25088);
    float* fA    = (float*)(smem + 50176);
    const int tid  = threadIdx.x;
    const int w    = tid >> 6;
    const int lane = tid & 63;

    // XCD-local tile mapping: hw blocks round-robin XCDs (bid%8). Put all 12
    // blocks of a tile on one XCD: xcd k hosts tiles k and k+8 (24 blocks/XCD).
    const int bhw  = blockIdx.x;
    const int xcd  = bhw & 7, slot = bhw >> 3;      // slot 0..23
    const int grp  = (slot >= 12) ? 1 : 0;
    const int sl   = slot - grp*12;                 // 0..11
    const int bt   = xcd + 8*grp;                   // tile 0..15
    const int b0   = bt * 32;

    if (sl < 8) {
        // ============ LAYER 1 : units [bs*32,+32), rows [b0,+32) ============
        const int bs = sl;
        float* bz = fA;           // [128]
        float* sG = fA + 128;     // gamma1 [256]
        float* sB = fA + 384;     // beta1  [256]
        if (tid < 128) {
            int g = tid >> 5, unit = bs*32 + (tid & 31);
            const float* bp = (g==0)?bf1:(g==1)?bi1:(g==2)?bg1:bo1;
            bz[tid] = bp[unit];
        }
        sG[tid] = gamma1[tid]; sB[tid] = beta1[tid];
        frag8 wH[2][12], wL[2][12];        // this wave's two n-tiles, resident
        #pragma unroll
        for (int e = 0; e < 2; ++e)
            #pragma unroll
            for (int kf = 0; kf < 12; ++kf) {
                size_t base = ((((size_t)bs*8 + (w*2+e))*12 + kf)*64 + lane)*8;
                wH[e][kf] = *(const frag8*)&w1h[base];
                wL[e][kf] = *(const frag8*)&w1l[base];
            }
        float cst[4] = {0.f, 0.f, 0.f, 0.f};   // c-state, registers for whole sequence
        __syncthreads();

        int slotW = 0, slotR = 0;
        for (int t = 0; t < S_; ++t) {
            // ---- x-part build (cols 0..128) — overlaps sibling publication
            {
                int row = tid >> 3, tc = tid & 7;
                const float* xp = &x[((size_t)(b0+row)*S_ + t)*IN_ + tc*16];
                #pragma unroll
                for (int g8 = 0; g8 < 2; ++g8) {
                    frag8 fh, fl;
                    #pragma unroll
                    for (int j = 0; j < 8; ++j) {
                        int col = tc*16 + g8*8 + j;
                        float v = (col < IN_) ? xp[g8*8+j] : 0.f;
                        u16 hi, lo; splitf(v, hi, lo);
                        fh[j] = (short)hi; fl[j] = (short)lo;
                    }
                    *(frag8*)&combH[row*392 + tc*16 + g8*8] = fh;
                    *(frag8*)&combL[row*392 + tc*16 + g8*8] = fl;
                }
            }
            // ---- parallel-lane poll: h1[t-1] published (8), slot freed by L2 (4)
            {
                u32 need = 0; u32* p = nullptr;
                if (tid < 8)                    { p = &a1[A1IDX(bt, tid)];    need = (u32)t; }
                else if (tid < 12 && t >= R)    { p = &dn2[A2IDX(bt, tid-8)]; need = (u32)(t - R + 1); }
                if (need) while (ld_flag(p) < need) {}
            }
            __syncthreads();
            // ---- h-part build (cols 128..384), consumer-side LN (coherent loads)
            build_ln<32>(combH, combL, 128, &h1x[((size_t)slotR*B_ + b0)*H1_], H1_,
                         1.f/H1_, sG, sB, tid, t == 0);
            __syncthreads();
            // ---- GEMM (weights in registers)
            facc4 acc[2][2];
            #pragma unroll
            for (int m = 0; m < 2; ++m)
                #pragma unroll
                for (int e = 0; e < 2; ++e) acc[m][e] = (facc4){0.f,0.f,0.f,0.f};
            gemm_step(combH, combL, wH, wL, lane, acc);
            __syncthreads();
            zdump(combH, combL, w, lane, acc);
            __syncthreads();
            // ---- gates + c/h update; publish raw h via coherent stores
            gates_update(combH, combL, bz, cst, tid,
                         &h1x[((size_t)slotW*B_ + b0)*H1_ + bs*32], H1_);
            __syncthreads();   // drains vmcnt -> all stores at coherence point
            if (tid == 0) st_flag(&a1[A1IDX(bt, bs)], (u32)(t + 1));
            slotR = slotW; slotW = (slotW + 1 == R) ? 0 : slotW + 1;
        }
    } else {
        // ============ LAYER 2 : units [vs*32,+32), rows [b0,+32) ============
        const int vs = sl - 8;
        float* bz  = fA;            // [128]
        float* sG1 = fA + 128;      // gamma1 [256]
        float* sB1 = fA + 384;
        float* sG2 = fA + 640;      // gamma2 [128]
        float* sB2 = fA + 768;
        if (tid < 128) {
            int g = tid >> 5, unit = vs*32 + (tid & 31);
            const float* bp = (g==0)?bf2:(g==1)?bi2:(g==2)?bg2:bo2;
            bz[tid] = bp[unit];
        }
        sG1[tid] = gamma1[tid]; sB1[tid] = beta1[tid];
        if (tid < 128) { sG2[tid] = gamma2[tid]; sB2[tid] = beta2[tid]; }
        frag8 wH[2][12], wL[2][12];
        #pragma unroll
        for (int e = 0; e < 2; ++e)
            #pragma unroll
            for (int kf = 0; kf < 12; ++kf) {
                size_t base = ((((size_t)vs*8 + (w*2+e))*12 + kf)*64 + lane)*8;
                wH[e][kf] = *(const frag8*)&w2h[base];
                wL[e][kf] = *(const frag8*)&w2l[base];
            }
        float cst[4] = {0.f, 0.f, 0.f, 0.f};
        __syncthreads();

        int slotW = 0, slotR = 0, slot1 = 0;
        for (int t = 0; t < S_; ++t) {
            // ---- merged poll: h1[t] (8 lanes) + h2[t-1] (4 lanes)
            {
                u32 need = 0; u32* p = nullptr;
                if (tid < 8)                  { p = &a1[A1IDX(bt, tid)];   need = (u32)(t + 1); }
                else if (tid < 12 && t > 0)   { p = &a2[A2IDX(bt, tid-8)]; need = (u32)t; }
                if (need) while (ld_flag(p) < need) {}
            }
            __syncthreads();
            build_ln<32>(combH, combL, 0, &h1x[((size_t)slot1*B_ + b0)*H1_], H1_,
                         1.f/H1_, sG1, sB1, tid, 0);
            build_ln<16>(combH, combL, 256, &h2x[((size_t)slotR*B_ + b0)*H2_], H2_,
                         1.f/H2_, sG2, sB2, tid, t == 0);
            __syncthreads();
            // consumption token: h1x slot may be recycled (reads done by barrier)
            if (tid == 0) st_flag(&dn2[A2IDX(bt, vs)], (u32)(t + 1));
            facc4 acc[2][2];
            #pragma unroll
            for (int m = 0; m < 2; ++m)
                #pragma unroll
                for (int e = 0; e < 2; ++e) acc[m][e] = (facc4){0.f,0.f,0.f,0.f};
            gemm_step(combH, combL, wH, wL, lane, acc);
            __syncthreads();
            zdump(combH, combL, w, lane, acc);
            __syncthreads();
            gates_update(combH, combL, bz, cst, tid,
                         &h2x[((size_t)slotW*B_ + b0)*H2_ + vs*32], H2_);
            __syncthreads();   // drains vmcnt
            if (tid == 0) st_flag(&a2[A2IDX(bt, vs)], (u32)(t + 1));
            slotR = slotW; slotW = (slotW + 1 == R) ? 0 : slotW + 1;
            slot1 = (slot1 + 1 == R) ? 0 : slot1 + 1;
        }
        // ---- final output: LN(h2[511]) by slice-0 blocks
        if (vs == 0) {
            if (tid < 4) { u32* p = &a2[A2IDX(bt, tid)]; while (ld_flag(p) < (u32)S_) {} }
            __syncthreads();
            int row = tid >> 3, tc = tid & 7;
            const float* p = &h2x[((size_t)slotR*B_ + b0 + row)*H2_];
            float v[16];
            #pragma unroll
            for (int g8 = 0; g8 < 2; ++g8)
                #pragma unroll
                for (int j = 0; j < 8; ++j)
                    v[g8*8+j] = ld_coh(&p[g8*64 + tc*8 + j]);
            float p4[4];
            #pragma unroll
            for (int j = 0; j < 4; ++j)
                p4[j] = (v[4*j] + v[4*j+1]) + (v[4*j+2] + v[4*j+3]);
            float s = (p4[0] + p4[1]) + (p4[2] + p4[3]);
            #pragma unroll
            for (int off = 1; off < 8; off <<= 1) s += __shfl_xor(s, off, 64);
            float mu = s * (1.f/H2_);
            #pragma unroll
            for (int j = 0; j < 4; ++j) {
                float d0 = v[4*j]   - mu, d1 = v[4*j+1] - mu;
                float d2 = v[4*j+2] - mu, d3 = v[4*j+3] - mu;
                p4[j] = (d0*d0 + d1*d1) + (d2*d2 + d3*d3);
            }
            float sq = (p4[0] + p4[1]) + (p4[2] + p4[3]);
            #pragma unroll
            for (int off = 1; off < 8; off <<= 1) sq += __shfl_xor(sq, off, 64);
            float rs = rsqrt_(__builtin_fmaf(sq, 1.f/H2_, 1e-5f));
            #pragma unroll
            for (int g8 = 0; g8 < 2; ++g8)
                #pragma unroll
                for (int j = 0; j < 8; ++j) {
                    int u = g8*64 + tc*8 + j;
                    float t_ = (v[g8*8+j]-mu)*rs;
                    out[((size_t)(b0+row))*H2_ + u] = __builtin_fmaf(t_, sG2[u], sB2[u]);
                }
        }
    }
}

extern "C" void kernel_launch(void* const* d_in, const int* in_sizes, int n_in,
                              void* d_out, int out_size, void* d_ws, size_t ws_size,
                              hipStream_t stream) {
    const float* x      = (const float*)d_in[0];
    const float* Wf1    = (const float*)d_in[1];
    const float* Wi1    = (const float*)d_in[2];
    const float* Wg1    = (const float*)d_in[3];
    const float* Wo1    = (const float*)d_in[4];
    const float* bf1    = (const float*)d_in[5];
    const float* bi1    = (const float*)d_in[6];
    const float* bg1    = (const float*)d_in[7];
    const float* bo1    = (const float*)d_in[8];
    const float* Wf2    = (const float*)d_in[9];
    const float* Wi2    = (const float*)d_in[10];
    const float* Wg2    = (const float*)d_in[11];
    const float* Wo2    = (const float*)d_in[12];
    const float* bf2    = (const float*)d_in[13];
    const float* bi2    = (const float*)d_in[14];
    const float* bg2    = (const float*)d_in[15];
    const float* bo2    = (const float*)d_in[16];
    const float* gamma1 = (const float*)d_in[17];
    const float* beta1  = (const float*)d_in[18];
    const float* gamma2 = (const float*)d_in[19];
    const float* beta2  = (const float*)d_in[20];

    char* ws = (char*)d_ws;
    u16* w1h = (u16*)(ws + OFF_W1H);
    u16* w1l = (u16*)(ws + OFF_W1L);
    u16* w2h = (u16*)(ws + OFF_W2H);
    u16* w2l = (u16*)(ws + OFF_W2L);
    u32* a1  = (u32*)(ws + OFF_AR1);
    u32* a2  = (u32*)(ws + OFF_AR2);
    u32* dn2 = (u32*)(ws + OFF_DN2);

    // exchange-ring depth: per slot 524288 B (h1) + 262144 B (h2)
    int R = (int)((ws_size - OFF_HX) / 786432);
    if (R > 16) R = 16;
    if (R < 2)  R = 2;
    float* h1x = (float*)(ws + OFF_HX);
    float* h2x = (float*)(ws + OFF_HX + (size_t)R * 524288);

    // zero the stamped flag words
    hipMemsetAsync(ws + OFF_AR1, 0, 65536, stream);

    prep_weights<<<2304, 256, 0, stream>>>(Wf1, Wi1, Wg1, Wo1, Wf2, Wi2, Wg2, Wo2,
                                           w1h, w1l, w2h, w2l);

    // Plain launch: 192 blocks < 256 CUs, 1 block/CU -> co-resident by construction.
    lstm_seq<<<dim3(NBLK), dim3(256), 53760, stream>>>(
        x, bf1, bi1, bg1, bo1, bf2, bi2, bg2, bo2,
        gamma1, beta1, gamma2, beta2,
        w1h, w1l, w2h, w2l,
        h1x, h2x, a1, a2, dn2,
        R, (float*)d_out);
}